// Round 7
// baseline (128.199 us; speedup 1.0000x reference)
//
#include <hip/hip_runtime.h>
#include <math.h>

// Hit-miss transform: out[i][j] = min_{di,dj}(x[i+di][j+dj] - Khit[di][dj])
//                               - max_{di,dj}(x[i+di][j+dj] - Kmiss[di][dj])
// H=W=4096 fp32 input, 5x5 kernels, output 4092x4092 fp32.
//
// R7: barrier-free wave-private staging. R2/R4/R6 all pinned at ~42us with
// ~2x-inflated VALUBusy (gfx94x SIMD-16 formula on SIMD-32 HW): the real
// bound is the stage->vmcnt(0)->compute serialization per block. Here each
// wave DMAs its OWN 260x8 input rows into its OWN 8.3KB LDS slice and reads
// only those -> no __syncthreads at all; waves overlap each other's DMA
// drains. Vertical halo rows staged per-wave (duplicate L2 reads, L3-hit).
// __launch_bounds__(256,4) lifts the 32-VGPR starvation.

constexpr int KS = 5;
constexpr int WW = 4096;
constexpr int HH = 4096;
constexpr int HO = 4092;
constexpr int WO = 4092;

constexpr int WROWS = 4;              // output rows per wave
constexpr int IROWS = WROWS + KS - 1; // 8 input rows staged per wave
constexpr int IWF   = 260;            // input floats per row (256 + 4 halo)
constexpr int WLDS  = IROWS * IWF;    // 2080 floats per wave slice

__device__ __forceinline__ float min3f(float a, float b, float c) {
    float d;
    asm("v_min3_f32 %0, %1, %2, %3" : "=v"(d) : "v"(a), "v"(b), "v"(c));
    return d;
}
__device__ __forceinline__ float max3f(float a, float b, float c) {
    float d;
    asm("v_max3_f32 %0, %1, %2, %3" : "=v"(d) : "v"(a), "v"(b), "v"(c));
    return d;
}

typedef __attribute__((address_space(1))) const void gvoid;
typedef __attribute__((address_space(3))) void svoid;

__global__ __launch_bounds__(256, 4) void hitmiss_kernel(
    const float* __restrict__ x,
    const float* __restrict__ kh,
    const float* __restrict__ km,
    float* __restrict__ out)
{
    __shared__ __attribute__((aligned(16))) float lds[4 * WLDS];  // 33280 B

    const int tid  = threadIdx.x;
    const int w    = tid >> 6;                    // wave id 0..3
    const int lane = tid & 63;
    const int c0   = blockIdx.x * 256;            // tile base col
    const int r0w  = blockIdx.y * 16 + w * 4;     // this wave's first output row

    float* ldsw = &lds[w * WLDS];                 // wave-private slice

    // Kernel weights: uniform -> scalar loads (overlap with DMA).
    float wh[KS * KS], wm[KS * KS];
#pragma unroll
    for (int i = 0; i < KS * KS; ++i) {
        wh[i] = kh[i];
        wm[i] = km[i];
    }

    // ---- Wave-private async staging: 8 rows x 260 floats ----
    // Row r: DMA1 (all lanes) covers floats 0..255; DMA2 (lane 0) floats
    // 256..259. LDS dest = wave-uniform base + lane*16 (HW rule).
    {
        // col address for DMA1: c0 + lane*4 <= 3840+252 = 4092 = WW-4, no clamp
        const int gc1 = c0 + lane * 4;
        int gc2 = c0 + 256; if (gc2 > WW - 4) gc2 = WW - 4;   // halo clamp
#pragma unroll
        for (int r = 0; r < IROWS; ++r) {
            int gr = r0w + r; if (gr > HH - 1) gr = HH - 1;   // bottom clamp
            const float* gp1 = x + (size_t)gr * WW + gc1;
            __builtin_amdgcn_global_load_lds((gvoid*)gp1, (svoid*)(ldsw + r * IWF), 16, 0, 0);
            if (lane < 1) {
                const float* gp2 = x + (size_t)gr * WW + gc2;
                __builtin_amdgcn_global_load_lds((gvoid*)gp2, (svoid*)(ldsw + r * IWF + 256), 16, 0, 0);
            }
        }
    }
    // No __syncthreads: each wave reads only its own slice; the compiler
    // inserts s_waitcnt vmcnt(0) before the first dependent ds_read.

    // ---- Compute: each lane 4 cols x 4 rows ----
    const int jl = lane * 4;          // col within slice
    const int jg = c0 + jl;           // global output col
    const bool colok = (jg <= WO - 4);

#pragma unroll
    for (int orow = 0; orow < WROWS; ++orow) {
        float mnA[4], mxA[4], mnP[4], mxP[4];

#pragma unroll
        for (int di = 0; di < KS; ++di) {
            const float* lp = ldsw + (orow + di) * IWF + jl;
            const float4 a = *reinterpret_cast<const float4*>(lp);
            const float4 b = *reinterpret_cast<const float4*>(lp + 4);
            const float v[8] = {a.x, a.y, a.z, a.w, b.x, b.y, b.z, b.w};
#pragma unroll
            for (int dj = 0; dj < KS; ++dj) {
                const int k = di * KS + dj;
                const float h = wh[k];
                const float m = wm[k];
#pragma unroll
                for (int p = 0; p < 4; ++p) {
                    const float t  = v[dj + p];
                    const float th = t - h;
                    const float tm = t - m;
                    if (k == 0) {
                        mnA[p] = th; mxA[p] = tm;
                    } else if (k & 1) {
                        mnP[p] = th; mxP[p] = tm;
                    } else {
                        mnA[p] = min3f(mnA[p], mnP[p], th);
                        mxA[p] = max3f(mxA[p], mxP[p], tm);
                    }
                }
            }
        }

        const int og = r0w + orow;
        if (colok && og < HO) {
            float4 o;
            o.x = mnA[0] - mxA[0];
            o.y = mnA[1] - mxA[1];
            o.z = mnA[2] - mxA[2];
            o.w = mnA[3] - mxA[3];
            *reinterpret_cast<float4*>(out + (size_t)og * WO + jg) = o;
        }
    }
}

extern "C" void kernel_launch(void* const* d_in, const int* in_sizes, int n_in,
                              void* d_out, int out_size, void* d_ws, size_t ws_size,
                              hipStream_t stream) {
    const float* x  = (const float*)d_in[0];
    const float* kh = (const float*)d_in[1];
    const float* km = (const float*)d_in[2];
    float* out = (float*)d_out;

    dim3 block(256, 1, 1);
    dim3 grid((WO + 255) / 256, (HO + 15) / 16, 1);  // 16 x 256
    hipLaunchKernelGGL(hitmiss_kernel, grid, block, 0, stream, x, kh, km, out);
}

// Round 8
// 127.227 us; speedup vs baseline: 1.0076x; 1.0076x over previous
//
#include <hip/hip_runtime.h>
#include <math.h>

// Hit-miss transform: out[i][j] = min_{di,dj}(x[i+di][j+dj] - Khit[di][dj])
//                               - max_{di,dj}(x[i+di][j+dj] - Kmiss[di][dj])
// H=W=4096 fp32 input, 5x5 kernels, output 4092x4092 fp32.
//
// R8: software-pipelined register streaming. All prior rounds are ~60%
// stall-bound (real VALU busy ~37%; gfx94x VALUBusy formula inflates 2x on
// SIMD-32). Each lane: 4 output cols x 10 output rows, 5-row x 8-float
// window in NAMED float4 vars rotated by macro-arg permutation (no dynamic
// indexing -> no scratch, unlike R3), next row's loads issued at the top of
// each ~620-cyc compute step so L2 latency is covered in-wave.
// __launch_bounds__(256,4) stops the allocator from re-sinking loads to
// chase 8-wave occupancy (the R2/R4 failure).

constexpr int KS  = 5;
constexpr int WW  = 4096;
constexpr int HH  = 4096;
constexpr int HO  = 4092;
constexpr int WO  = 4092;
constexpr int RPT = 10;            // output rows per wave

__device__ __forceinline__ float min3f(float a, float b, float c) {
    float d;
    asm("v_min3_f32 %0, %1, %2, %3" : "=v"(d) : "v"(a), "v"(b), "v"(c));
    return d;
}
__device__ __forceinline__ float max3f(float a, float b, float c) {
    float d;
    asm("v_max3_f32 %0, %1, %2, %3" : "=v"(d) : "v"(a), "v"(b), "v"(c));
    return d;
}

// One window-row's contribution. DI = kernel row (compile-time so the k==0
// seed and parity pattern are static). Accs are arrays with constant
// indices (SROA-proven in R1-R7), weights read straight from global
// (uniform -> s_load, hoisted & CSE'd across the 10 steps).
template<int DI>
__device__ __forceinline__ void rowupd(float4 A, float4 B,
    const float* __restrict__ kh, const float* __restrict__ km,
    float (&mnA)[4], float (&mxA)[4], float (&mnP)[4], float (&mxP)[4])
{
    const float v[8] = {A.x, A.y, A.z, A.w, B.x, B.y, B.z, B.w};
#pragma unroll
    for (int dj = 0; dj < KS; ++dj) {
        const int k = DI * KS + dj;
        const float h = kh[k];
        const float m = km[k];
#pragma unroll
        for (int p = 0; p < 4; ++p) {
            const float t  = v[dj + p];
            const float th = t - h;
            const float tm = t - m;
            if (k == 0) {
                mnA[p] = th; mxA[p] = tm;
            } else if (k & 1) {
                mnP[p] = th; mxP[p] = tm;
            } else {
                mnA[p] = min3f(mnA[p], mnP[p], th);   // 12 min3/px total
                mxA[p] = max3f(mxA[p], mxP[p], tm);
            }
        }
    }
}

// Load input row (r0w + T) window: 8 floats as 2 float4.
#define LOADROW(A, B, T) do {                                              \
    int gr_ = r0w + (T); if (gr_ > HH - 1) gr_ = HH - 1;                   \
    const float* rp_ = x + (size_t)gr_ * WW;                               \
    (A) = *reinterpret_cast<const float4*>(rp_ + gc1);                     \
    (B) = *reinterpret_cast<const float4*>(rp_ + gc2);                     \
} while (0)

// One output row: compute from window rows (A0..A4 = input rows T..T+4),
// store, then refill the dying slot (A0/B0) with input row T+5.
#define STEP(A0,B0,A1,B1,A2,B2,A3,B3,A4,B4, T, DOLOAD) do {                \
    float mnA[4], mxA[4], mnP[4], mxP[4];                                  \
    rowupd<0>(A0, B0, kh, km, mnA, mxA, mnP, mxP);                         \
    rowupd<1>(A1, B1, kh, km, mnA, mxA, mnP, mxP);                         \
    rowupd<2>(A2, B2, kh, km, mnA, mxA, mnP, mxP);                         \
    rowupd<3>(A3, B3, kh, km, mnA, mxA, mnP, mxP);                         \
    rowupd<4>(A4, B4, kh, km, mnA, mxA, mnP, mxP);                         \
    const int og_ = r0w + (T);                                             \
    if (colok && og_ < HO) {                                               \
        float4 o_;                                                         \
        o_.x = mnA[0] - mxA[0];                                            \
        o_.y = mnA[1] - mxA[1];                                            \
        o_.z = mnA[2] - mxA[2];                                            \
        o_.w = mnA[3] - mxA[3];                                            \
        *reinterpret_cast<float4*>(out + (size_t)og_ * WO + jg) = o_;      \
    }                                                                      \
    if (DOLOAD) LOADROW(A0, B0, (T) + 5);                                  \
} while (0)

__global__ __launch_bounds__(256, 4) void hitmiss_kernel(
    const float* __restrict__ x,
    const float* __restrict__ kh,
    const float* __restrict__ km,
    float* __restrict__ out)
{
    const int tid  = threadIdx.x;
    const int w    = tid >> 6;                       // wave 0..3
    const int lane = tid & 63;
    const int c0   = blockIdx.x * 256;               // column band
    const int r0w  = (blockIdx.y * 4 + w) * RPT;     // this wave's first row

    const int gc1 = c0 + lane * 4;                   // <= 4092 always
    int gc2 = gc1 + 4; if (gc2 > WW - 4) gc2 = WW - 4;   // lane 63 @ last band
    const int jg = gc1;
    const bool colok = (jg <= WO - 4);

    float4 a0, b0, a1, b1, a2, b2, a3, b3, a4, b4;
    LOADROW(a0, b0, 0);
    LOADROW(a1, b1, 1);
    LOADROW(a2, b2, 2);
    LOADROW(a3, b3, 3);
    LOADROW(a4, b4, 4);

    // Two full window rotations = 10 output rows. Slot names are permuted
    // statically; last step skips its (useless) refill.
    STEP(a0,b0, a1,b1, a2,b2, a3,b3, a4,b4, 0, true);
    STEP(a1,b1, a2,b2, a3,b3, a4,b4, a0,b0, 1, true);
    STEP(a2,b2, a3,b3, a4,b4, a0,b0, a1,b1, 2, true);
    STEP(a3,b3, a4,b4, a0,b0, a1,b1, a2,b2, 3, true);
    STEP(a4,b4, a0,b0, a1,b1, a2,b2, a3,b3, 4, true);
    STEP(a0,b0, a1,b1, a2,b2, a3,b3, a4,b4, 5, true);
    STEP(a1,b1, a2,b2, a3,b3, a4,b4, a0,b0, 6, true);
    STEP(a2,b2, a3,b3, a4,b4, a0,b0, a1,b1, 7, true);
    STEP(a3,b3, a4,b4, a0,b0, a1,b1, a2,b2, 8, true);
    STEP(a4,b4, a0,b0, a1,b1, a2,b2, a3,b3, 9, false);
}

extern "C" void kernel_launch(void* const* d_in, const int* in_sizes, int n_in,
                              void* d_out, int out_size, void* d_ws, size_t ws_size,
                              hipStream_t stream) {
    const float* x  = (const float*)d_in[0];
    const float* kh = (const float*)d_in[1];
    const float* km = (const float*)d_in[2];
    float* out = (float*)d_out;

    dim3 block(256, 1, 1);
    // 16 column bands x ceil(4092/40) row bands; tail rows guarded in-kernel.
    dim3 grid((WO + 255) / 256, (HO + 4 * RPT - 1) / (4 * RPT), 1);  // 16 x 103
    hipLaunchKernelGGL(hitmiss_kernel, grid, block, 0, stream, x, kh, km, out);
}